// Round 6
// baseline (444.939 us; speedup 1.0000x reference)
//
#include <hip/hip_runtime.h>

#define C_CH 173
#define L_IN 400
#define EPSV 1e-5f
#define KFEAT 55360  // C*32*10

typedef __fp16   fp16x2 __attribute__((ext_vector_type(2)));
typedef _Float16 f16x8  __attribute__((ext_vector_type(8)));
typedef float    f32x16 __attribute__((ext_vector_type(16)));

#define Y1T_STRIDE 36   // f16/row = 18 dwords: even (8B-aligned b64), 2-way = free
#define Y1T_ROWS   422  // row r = y1 time (r-3); rows 0..2 and 403..421 zeroed

// 8-lane max via DPP (pure VALU, no DS pipe)
template <int CTRL>
__device__ __forceinline__ float dppf(float v) {
    int s = __builtin_bit_cast(int, v);
    int r = __builtin_amdgcn_update_dpp(0, s, CTRL, 0xF, 0xF, true);
    return __builtin_bit_cast(float, r);
}

// ---------------------------------------------------------------------------
// Tower kernel: one block per (channel c, batch b). 320 threads = 5 waves.
//  phase 1: stage x, w1, w2T(f16,[dt][f][g]), BN consts, zero y1T halos
//  phase 2: conv1(f32) quad-t sliding window (3x b128 per 4 outputs) -> y1T
//  phase 3: conv2 via 7x mfma_32x32x16_f16; BN+ReLU in regs; 8-wide DPP max
//           -> segmax[f][50] f16
//  phase 4: pool = max of 5 segments -> feat (f16)
// LDS 43344 B -> rounds to 43520: 3 blocks fit under the ~128 KiB
// residency limit inferred from R3/R4 occupancy (R4's 47104 B -> only 2).
// ---------------------------------------------------------------------------
__global__ __launch_bounds__(320) void tower_kernel(
    const float* __restrict__ x,
    const float* __restrict__ w1, const float* __restrict__ b1,
    const float* __restrict__ g1, const float* __restrict__ beta1,
    const float* __restrict__ m1, const float* __restrict__ v1,
    const float* __restrict__ w2, const float* __restrict__ b2,
    const float* __restrict__ g2, const float* __restrict__ beta2,
    const float* __restrict__ m2, const float* __restrict__ v2,
    _Float16* __restrict__ featH, float* __restrict__ h_ws)
{
    __shared__ __align__(16) float    x_s[408];
    __shared__ __align__(16) float    w1_s[144];
    __shared__ __align__(16) _Float16 y1T_s[Y1T_ROWS * Y1T_STRIDE];
    __shared__ __align__(16) _Float16 w2T_s[7 * 512];        // [dt][f][g]
    __shared__ _Float16               segmax_s[32 * 50];     // [f][seg] f16
    __shared__ float scale1_s[16], shift1_s[16], scale2_s[32], shift2_s[32];

    const int c   = blockIdx.x;
    const int b   = blockIdx.y;
    const int tid = threadIdx.x;

    if (c == 0 && b == 0) {
        for (int i = tid; i < 128 * 64; i += 320) h_ws[i] = 0.0f;
    }

    // ---- phase 1: staging ----
    const float* xrow = x + ((size_t)b * C_CH + c) * L_IN;
    for (int i = tid; i < 408; i += 320)
        x_s[i] = (i >= 4 && i < 404) ? xrow[i - 4] : 0.0f;

    for (int i = tid; i < 144; i += 320)
        w1_s[i] = w1[c * 144 + i];

    // w2 via float4 (896 xfers), scatter to w2T[dt][f][g] f16
    for (int idx = tid; idx < 896; idx += 320) {
        float4 v = *(const float4*)(w2 + (size_t)c * 3584 + idx * 4);
        int i0 = idx * 4;
        int f = i0 / 112;
        int r = i0 - f * 112;
        float vv[4] = {v.x, v.y, v.z, v.w};
#pragma unroll
        for (int k = 0; k < 4; ++k) {
            int rr = r + k;                 // 112 % 4 == 0 -> same f
            int g = rr / 7, dt = rr - g * 7;
            w2T_s[dt * 512 + f * 16 + g] = (_Float16)vv[k];
        }
    }

    // zero y1T halo rows 0..2 and 403..421 (22 rows x 18 dwords)
    for (int i = tid; i < 22 * 18; i += 320) {
        int r = i / 18, cidx = i - r * 18;
        int row = (r < 3) ? r : (400 + r);
        ((int*)y1T_s)[row * 18 + cidx] = 0;
    }

    if (tid < 16) {
        int cf = c * 16 + tid;
        float inv = g1[cf] * rsqrtf(v1[cf] + EPSV);
        scale1_s[tid] = inv;
        shift1_s[tid] = (b1[cf] - m1[cf]) * inv + beta1[cf];
    }
    if (tid >= 64 && tid < 96) {
        int f = tid - 64;
        int cf = c * 32 + f;
        float inv = g2[cf] * rsqrtf(v2[cf] + EPSV);
        scale2_s[f] = inv;
        shift2_s[f] = (b2[cf] - m2[cf]) * inv + beta2[cf];
    }
    __syncthreads();

    // ---- phase 2: conv1 + BN + ReLU -> y1T (quad-t, b128 x-reads) ----
    // idx = tid + it*320: g = idx&15 (invariant), quad = idx>>4.
    // Lanes 0..15 share a quad -> x_s b128 broadcast; quads 0..3 within a
    // wave hit disjoint bank groups. w1/scales hoisted to registers.
    {
        const int g0 = tid & 15;
        float wreg[9];
#pragma unroll
        for (int k = 0; k < 9; ++k) wreg[k] = w1_s[g0 * 9 + k];
        const float s1  = scale1_s[g0];
        const float sh1 = shift1_s[g0];

#pragma unroll
        for (int it = 0; it < 5; ++it) {
            const int idx = tid + it * 320;
            const int t0  = (idx >> 4) * 4;
            float xv[12];
            const float4 a0 = *(const float4*)(x_s + t0);
            const float4 a1 = *(const float4*)(x_s + t0 + 4);
            const float4 a2 = *(const float4*)(x_s + t0 + 8);
            xv[0] = a0.x; xv[1] = a0.y; xv[2]  = a0.z; xv[3]  = a0.w;
            xv[4] = a1.x; xv[5] = a1.y; xv[6]  = a1.z; xv[7]  = a1.w;
            xv[8] = a2.x; xv[9] = a2.y; xv[10] = a2.z; xv[11] = a2.w;
#pragma unroll
            for (int j = 0; j < 4; ++j) {
                float acc = 0.0f;
#pragma unroll
                for (int k = 0; k < 9; ++k) acc += wreg[k] * xv[j + k];
                float val = acc * s1 + sh1;
                val = val > 0.0f ? val : 0.0f;
                y1T_s[(t0 + j + 3) * Y1T_STRIDE + g0] = (_Float16)val;
            }
        }
    }
    __syncthreads();

    // ---- phase 3: conv2 MFMA + BN/ReLU + in-register 8-seg max ----
    {
        const int wv    = tid >> 6;
        const int lane  = tid & 63;
        const int nlane = lane & 31;
        const int half  = lane >> 5;

        union F8q { int4 q; f16x8 h; } af[7];
#pragma unroll
        for (int dt = 0; dt < 7; ++dt)
            af[dt].q = *(const int4*)((const int*)w2T_s + dt * 256 + nlane * 8 + half * 4);

        // hoist BN consts (LDS stores inside the loop block compiler hoisting)
        float sc[16], sh[16];
#pragma unroll
        for (int reg = 0; reg < 16; ++reg) {
            int f = (reg & 3) + 8 * (reg >> 2) + 4 * half;
            sc[reg] = scale2_s[f];
            sh[reg] = shift2_s[f];
        }

        for (int tile = wv; tile < 13; tile += 5) {
            const int t0 = tile * 32 + nlane;
            f32x16 acc;
#pragma unroll
            for (int i = 0; i < 16; ++i) acc[i] = 0.0f;

#pragma unroll
            for (int dt = 0; dt < 7; ++dt) {
                const int* p = (const int*)y1T_s + (t0 + dt) * 18 + half * 4;
                union { int2 d[2]; f16x8 h; } bf;
                bf.d[0] = *(const int2*)p;
                bf.d[1] = *(const int2*)(p + 2);
                acc = __builtin_amdgcn_mfma_f32_32x32x16_f16(af[dt].h, bf.h, acc, 0, 0, 0);
            }

            const bool wr  = ((nlane & 7) == 0) && (t0 < 400);
            const int  seg = t0 >> 3;       // segment of 8 t-values
#pragma unroll
            for (int reg = 0; reg < 16; ++reg) {
                int f = (reg & 3) + 8 * (reg >> 2) + 4 * half;
                float v = acc[reg] * sc[reg] + sh[reg];
                v = fmaxf(v, 0.0f);
                v = fmaxf(v, dppf<0xB1>(v));    // xor 1 (quad_perm 1,0,3,2)
                v = fmaxf(v, dppf<0x4E>(v));    // xor 2 (quad_perm 2,3,0,1)
                v = fmaxf(v, dppf<0x141>(v));   // row_half_mirror (combine quads)
                if (wr) segmax_s[f * 50 + seg] = (_Float16)v;
            }
        }
    }
    __syncthreads();

    // ---- phase 4: pool(40) = max of 5 segment-maxes -> feat f16 ----
    {
        const int f = tid & 31;
        const int p = tid >> 5;
        float m = 0.0f;                      // post-ReLU values >= 0
#pragma unroll
        for (int k = 0; k < 5; ++k)
            m = fmaxf(m, (float)segmax_s[f * 50 + p * 5 + k]);
        featH[(size_t)b * KFEAT + (c * 32 + f) * 10 + p] = (_Float16)m;
    }
}

// ---------------------------------------------------------------------------
// FC1 as f16 MFMA GEMM, split-K, NO LDS: fragments loaded directly from
// global. 692 blocks x KC=80; 256 threads = 4 waves; wave = j-tile (32 rows),
// both N-tiles (batches 0-31, 32-63). Per-lane K-slices are contiguous
// (320 B A / 160 B B) so cachelines are fully consumed across s-steps.
// ---------------------------------------------------------------------------
__global__ __launch_bounds__(256) void fc1_kernel(
    const _Float16* __restrict__ featH, const float* __restrict__ wc1,
    float* __restrict__ h_ws)
{
    const int tid   = threadIdx.x;
    const int k0    = blockIdx.x * 80;
    const int lane  = tid & 63;
    const int wv    = tid >> 6;
    const int nlane = lane & 31;
    const int half  = lane >> 5;
    const int jrow  = wv * 32 + nlane;

    const float*    ap  = wc1   + (size_t)jrow * KFEAT + k0 + half * 8;
    const _Float16* b0p = featH + (size_t)nlane * KFEAT + k0 + half * 8;
    const _Float16* b1p = featH + (size_t)(nlane + 32) * KFEAT + k0 + half * 8;

    f32x16 acc0, acc1;
#pragma unroll
    for (int i = 0; i < 16; ++i) { acc0[i] = 0.0f; acc1[i] = 0.0f; }

#pragma unroll
    for (int s = 0; s < 5; ++s) {
        const float4 aw0 = *(const float4*)(ap + s * 16);
        const float4 aw1 = *(const float4*)(ap + s * 16 + 4);
        union { fp16x2 v2[4]; f16x8 h; } a;
        a.v2[0] = __builtin_amdgcn_cvt_pkrtz(aw0.x, aw0.y);
        a.v2[1] = __builtin_amdgcn_cvt_pkrtz(aw0.z, aw0.w);
        a.v2[2] = __builtin_amdgcn_cvt_pkrtz(aw1.x, aw1.y);
        a.v2[3] = __builtin_amdgcn_cvt_pkrtz(aw1.z, aw1.w);

        union { int4 q; f16x8 h; } b0, b1;
        b0.q = *(const int4*)(b0p + s * 16);
        b1.q = *(const int4*)(b1p + s * 16);

        acc0 = __builtin_amdgcn_mfma_f32_32x32x16_f16(a.h, b0.h, acc0, 0, 0, 0);
        acc1 = __builtin_amdgcn_mfma_f32_32x32x16_f16(a.h, b1.h, acc1, 0, 0, 0);
    }

#pragma unroll
    for (int reg = 0; reg < 16; ++reg) {
        int j = wv * 32 + (reg & 3) + 8 * (reg >> 2) + 4 * half;
        atomicAdd(&h_ws[j * 64 + nlane],      acc0[reg]);
        atomicAdd(&h_ws[j * 64 + 32 + nlane], acc1[reg]);
    }
}

// ---------------------------------------------------------------------------
// FC2: out[b] = bc2 + sum_j wc2[j] * relu(h[j][b] + bc1[j])
// ---------------------------------------------------------------------------
__global__ __launch_bounds__(64) void fc2_kernel(
    const float* __restrict__ h_ws, const float* __restrict__ bc1,
    const float* __restrict__ wc2, const float* __restrict__ bc2,
    float* __restrict__ out)
{
    const int b = threadIdx.x;
    float acc = bc2[0];
    for (int j = 0; j < 128; ++j) {
        float hv = h_ws[j * 64 + b] + bc1[j];
        hv = hv > 0.0f ? hv : 0.0f;
        acc += wc2[j] * hv;
    }
    out[b] = acc;
}

extern "C" void kernel_launch(void* const* d_in, const int* in_sizes, int n_in,
                              void* d_out, int out_size, void* d_ws, size_t ws_size,
                              hipStream_t stream)
{
    const float* x     = (const float*)d_in[0];
    const float* w1    = (const float*)d_in[1];
    const float* b1    = (const float*)d_in[2];
    const float* g1    = (const float*)d_in[3];
    const float* beta1 = (const float*)d_in[4];
    const float* m1    = (const float*)d_in[5];
    const float* v1    = (const float*)d_in[6];
    const float* w2    = (const float*)d_in[7];
    const float* b2    = (const float*)d_in[8];
    const float* g2    = (const float*)d_in[9];
    const float* beta2 = (const float*)d_in[10];
    const float* m2    = (const float*)d_in[11];
    const float* v2    = (const float*)d_in[12];
    const float* wc1   = (const float*)d_in[13];
    const float* bc1   = (const float*)d_in[14];
    const float* wc2   = (const float*)d_in[15];
    const float* bc2   = (const float*)d_in[16];

    _Float16* featH = (_Float16*)d_ws;                                // 64*55360 f16 = 7.09 MB
    float*    h_ws  = (float*)((char*)d_ws + (size_t)64 * KFEAT * 2); // 128*64 f32

    dim3 gtower(C_CH, 64);
    hipLaunchKernelGGL(tower_kernel, gtower, dim3(320), 0, stream,
                       x, w1, b1, g1, beta1, m1, v1,
                       w2, b2, g2, beta2, m2, v2, featH, h_ws);

    hipLaunchKernelGGL(fc1_kernel, dim3(692), dim3(256), 0, stream,
                       featH, wc1, h_ws);

    hipLaunchKernelGGL(fc2_kernel, dim3(1), dim3(64), 0, stream,
                       h_ws, bc1, wc2, bc2, (float*)d_out);
}